// Round 3
// baseline (315.776 us; speedup 1.0000x reference)
//
#include <hip/hip_runtime.h>
#include <hip/hip_bf16.h>
#include <math.h>

typedef __attribute__((ext_vector_type(4))) float f32x4;
typedef __attribute__((ext_vector_type(8))) short short8;
typedef __attribute__((ext_vector_type(4))) unsigned short ushort4_t;

#define B_  4
#define S_  2048
#define D_  1024
#define NH_ 16
#define HD_ 64

__device__ __forceinline__ unsigned short f2bf(float f) {
  unsigned u = __builtin_bit_cast(unsigned, f);
  u += 0x7FFFu + ((u >> 16) & 1u);   // RNE
  return (unsigned short)(u >> 16);
}

__device__ __forceinline__ void gload_lds16(const void* g, void* l) {
  __builtin_amdgcn_global_load_lds(
      (const __attribute__((address_space(1))) unsigned int*)g,
      (__attribute__((address_space(3))) unsigned int*)l, 16, 0, 0);
}

// ---------------- fp32 -> bf16 converts (fused launches) ----------------
__global__ void cvt3_f32_to_bf16(const float* __restrict__ a,
                                 const float* __restrict__ b,
                                 const float* __restrict__ c,
                                 unsigned short* __restrict__ oa,
                                 unsigned short* __restrict__ ob,
                                 unsigned short* __restrict__ oc, int n4) {
  int i = blockIdx.x * 256 + threadIdx.x;
  if (i >= n4) return;
  const float* in = blockIdx.y == 0 ? a : (blockIdx.y == 1 ? b : c);
  unsigned short* out = blockIdx.y == 0 ? oa : (blockIdx.y == 1 ? ob : oc);
  const float4 f = reinterpret_cast<const float4*>(in)[i];
  ushort4_t r;
  r.x = f2bf(f.x); r.y = f2bf(f.y); r.z = f2bf(f.z); r.w = f2bf(f.w);
  reinterpret_cast<ushort4_t*>(out)[i] = r;
}

__global__ void cvt4_f32_to_bf16(const float* __restrict__ a,
                                 const float* __restrict__ b,
                                 const float* __restrict__ c,
                                 const float* __restrict__ d,
                                 unsigned short* __restrict__ oa,
                                 unsigned short* __restrict__ ob,
                                 unsigned short* __restrict__ oc,
                                 unsigned short* __restrict__ od, int n4) {
  int i = blockIdx.x * 256 + threadIdx.x;
  if (i >= n4) return;
  const float* in = blockIdx.y == 0 ? a : (blockIdx.y == 1 ? b : (blockIdx.y == 2 ? c : d));
  unsigned short* out = blockIdx.y == 0 ? oa : (blockIdx.y == 1 ? ob : (blockIdx.y == 2 ? oc : od));
  const float4 f = reinterpret_cast<const float4*>(in)[i];
  ushort4_t r;
  r.x = f2bf(f.x); r.y = f2bf(f.y); r.z = f2bf(f.z); r.w = f2bf(f.w);
  reinterpret_cast<ushort4_t*>(out)[i] = r;
}

// ---------------- GEMM body: C[M,N] = A[M,K] @ W[N,K]^T + bias ----------------
template <int OUT_F32>
__device__ __forceinline__ void gemm_body(
    const unsigned short* __restrict__ A,
    const unsigned short* __restrict__ W,
    const float* __restrict__ bias,
    void* __restrict__ Cout, int trans,
    unsigned short* At, unsigned short* Wt, int m0, int n0) {
  constexpr int K = 1024;
  const int tid = threadIdx.x;
  const int wave = tid >> 6, lane = tid & 63;
  f32x4 acc[4][4] = {};

  const int srow = tid >> 3;
  const int scol8 = tid & 7;

  for (int kt = 0; kt < K; kt += 64) {
#pragma unroll
    for (int c = 0; c < 4; ++c) {
      const int row = c * 32 + srow;
      const int col = (scol8 ^ (row & 7)) << 3;
      gload_lds16(A + (size_t)(m0 + row) * K + kt + col,
                  (char*)At + c * 4096 + wave * 1024);
    }
#pragma unroll
    for (int c = 0; c < 4; ++c) {
      const int row = c * 32 + srow;
      const int col = (scol8 ^ (row & 7)) << 3;
      gload_lds16(W + (size_t)(n0 + row) * K + kt + col,
                  (char*)Wt + c * 4096 + wave * 1024);
    }
    asm volatile("s_waitcnt vmcnt(0)" ::: "memory");
    __syncthreads();

    const int wr = (wave >> 1) * 64, wc = (wave & 1) * 64;
#pragma unroll
    for (int kk = 0; kk < 2; ++kk) {
      short8 af[4], wf[4];
#pragma unroll
      for (int m = 0; m < 4; ++m) {
        const int row = wr + m * 16 + (lane & 15);
        const int colb = ((kk * 32 + (lane >> 4) * 8) * 2) ^ ((row & 7) << 4);
        af[m] = *(const short8*)((const char*)At + row * 128 + colb);
      }
#pragma unroll
      for (int n = 0; n < 4; ++n) {
        const int row = wc + n * 16 + (lane & 15);
        const int colb = ((kk * 32 + (lane >> 4) * 8) * 2) ^ ((row & 7) << 4);
        wf[n] = *(const short8*)((const char*)Wt + row * 128 + colb);
      }
#pragma unroll
      for (int m = 0; m < 4; ++m)
#pragma unroll
        for (int n = 0; n < 4; ++n)
          acc[m][n] = __builtin_amdgcn_mfma_f32_16x16x32_bf16(af[m], wf[n], acc[m][n], 0, 0, 0);
    }
    __syncthreads();
  }

  const int wr = (wave >> 1) * 64, wc = (wave & 1) * 64;
  const int g = lane >> 4, cl = lane & 15;
#pragma unroll
  for (int m = 0; m < 4; ++m) {
#pragma unroll
    for (int n = 0; n < 4; ++n) {
      const int ng = n0 + wc + n * 16 + cl;
      const float bv = bias[ng];
      if (trans) {
        const int mg = m0 + wr + m * 16 + g * 4;
        const int bb = mg >> 11;
        const int ss = mg & 2047;
        ushort4_t pk;
        pk.x = f2bf(acc[m][n][0] + bv);
        pk.y = f2bf(acc[m][n][1] + bv);
        pk.z = f2bf(acc[m][n][2] + bv);
        pk.w = f2bf(acc[m][n][3] + bv);
        *(ushort4_t*)((unsigned short*)Cout + ((size_t)bb * 1024 + ng) * 2048 + ss) = pk;
      } else {
#pragma unroll
        for (int r = 0; r < 4; ++r) {
          const int mg = m0 + wr + m * 16 + g * 4 + r;
          const float v = acc[m][n][r] + bv;
          if (OUT_F32)
            ((float*)Cout)[(size_t)mg * 1024 + ng] = v;
          else
            ((unsigned short*)Cout)[(size_t)mg * 1024 + ng] = f2bf(v);
        }
      }
    }
  }
}

// fused Q/K/V projection (grid.z selects which)
__global__ __launch_bounds__(256) void gemm_qkv(
    const unsigned short* __restrict__ qb, const unsigned short* __restrict__ kb,
    const unsigned short* __restrict__ vb,
    const unsigned short* __restrict__ Wqb, const unsigned short* __restrict__ Wkb,
    const unsigned short* __restrict__ Wvb,
    const float* __restrict__ bq, const float* __restrict__ bk,
    const float* __restrict__ bv,
    unsigned short* __restrict__ Qp, unsigned short* __restrict__ Kp,
    unsigned short* __restrict__ Vt) {
  __shared__ unsigned short At[128 * 64];
  __shared__ unsigned short Wt[128 * 64];
  const int z = blockIdx.z;
  const unsigned short* A = z == 0 ? qb : (z == 1 ? kb : vb);
  const unsigned short* W = z == 0 ? Wqb : (z == 1 ? Wkb : Wvb);
  const float* bias = z == 0 ? bq : (z == 1 ? bk : bv);
  void* out = z == 0 ? (void*)Qp : (z == 1 ? (void*)Kp : (void*)Vt);
  gemm_body<0>(A, W, bias, out, z == 2, At, Wt, blockIdx.y * 128, blockIdx.x * 128);
}

__global__ __launch_bounds__(256) void gemm_o(
    const unsigned short* __restrict__ A, const unsigned short* __restrict__ W,
    const float* __restrict__ bias, float* __restrict__ out) {
  __shared__ unsigned short At[128 * 64];
  __shared__ unsigned short Wt[128 * 64];
  gemm_body<1>(A, W, bias, out, 0, At, Wt, blockIdx.y * 128, blockIdx.x * 128);
}

// ---------------- flash attention (causal + padding mask) ----------------
// 1024 blocks; per-CU balance via qtile = ((y>>4)&1) ? 15-x : x.
__global__ __launch_bounds__(256) void attn_fwd(
    const unsigned short* __restrict__ Qp,   // [B*S][1024]
    const unsigned short* __restrict__ Kp,   // [B*S][1024]
    const unsigned short* __restrict__ Vt,   // [B][1024][2048] (transposed)
    const unsigned char* __restrict__ pmask, // [B][2048]
    unsigned short* __restrict__ Out) {      // [B*S][1024]
  __shared__ unsigned short Kt[64 * 64];
  __shared__ unsigned short Vl[64 * 64];
  __shared__ unsigned short Pl[4][32 * 72];
  __shared__ unsigned char msk[64];

  const int tid = threadIdx.x;
  const int wave = tid >> 6, lane = tid & 63;
  const int g = lane >> 4, cl = lane & 15;
  const int bh = blockIdx.y, b = bh >> 4, h = bh & 15;
  const int srow = tid >> 3, scol8 = tid & 7;
  const float cs = 0.125f * 1.44269504088896f;  // exp2-domain scale

  const int qtile = ((bh >> 4) & 1) ? (15 - (int)blockIdx.x) : (int)blockIdx.x;
  const int q0 = qtile * 128;
  const int qw = q0 + wave * 32;

  short8 qf[2][2];
#pragma unroll
  for (int m = 0; m < 2; ++m)
#pragma unroll
    for (int kk = 0; kk < 2; ++kk)
      qf[m][kk] = *(const short8*)(Qp + (size_t)(b * S_ + qw + m * 16 + cl) * D_ +
                                   h * HD_ + kk * 32 + g * 8);

  float mrow[2][4], lrow[2][4];
  f32x4 oacc[2][4] = {};
#pragma unroll
  for (int m = 0; m < 2; ++m)
#pragma unroll
    for (int r = 0; r < 4; ++r) { mrow[m][r] = -INFINITY; lrow[m][r] = 0.f; }

  const int kvend = q0 + 128;
#pragma unroll 1
  for (int kv0 = 0; kv0 < kvend; kv0 += 64) {
#pragma unroll
    for (int c = 0; c < 2; ++c) {
      const int row = c * 32 + srow;
      const int col = (scol8 ^ (row & 7)) << 3;
      gload_lds16(Kp + (size_t)(b * S_ + kv0 + row) * D_ + h * HD_ + col,
                  (char*)Kt + c * 4096 + wave * 1024);
      gload_lds16(Vt + ((size_t)b * D_ + h * HD_ + row) * S_ + kv0 + col,
                  (char*)Vl + c * 4096 + wave * 1024);
    }
    if (tid < 64) msk[tid] = pmask[b * S_ + kv0 + tid];
    asm volatile("s_waitcnt vmcnt(0)" ::: "memory");
    __syncthreads();

    const bool active = (kv0 <= qw + 31);   // wave-uniform
    if (active) {
      // S = Q @ K^T
      f32x4 sc[2][4] = {};
#pragma unroll
      for (int kk = 0; kk < 2; ++kk) {
        short8 kf[4];
#pragma unroll
        for (int n = 0; n < 4; ++n) {
          const int row = n * 16 + cl;
          const int colb = ((kk * 32 + g * 8) * 2) ^ ((row & 7) << 4);
          kf[n] = *(const short8*)((const char*)Kt + row * 128 + colb);
        }
#pragma unroll
        for (int m = 0; m < 2; ++m)
#pragma unroll
          for (int n = 0; n < 4; ++n)
            sc[m][n] = __builtin_amdgcn_mfma_f32_16x16x32_bf16(qf[m][kk], kf[n], sc[m][n], 0, 0, 0);
      }

      // padding-mask addend (per-lane, per n-block)
      float pm_add[4];
#pragma unroll
      for (int n = 0; n < 4; ++n)
        pm_add[n] = msk[n * 16 + cl] ? -1e30f : 0.0f;

      // scale (exp2 domain) + masks
      const bool anymask = (kv0 + 63 > qw);
      if (anymask) {
#pragma unroll
        for (int m = 0; m < 2; ++m)
#pragma unroll
          for (int n = 0; n < 4; ++n) {
            const int kv = kv0 + n * 16 + cl;
#pragma unroll
            for (int r = 0; r < 4; ++r) {
              const int qg = qw + m * 16 + g * 4 + r;
              const float s = fmaf(sc[m][n][r], cs, pm_add[n]);
              sc[m][n][r] = (kv > qg) ? -1e30f : s;
            }
          }
      } else {
#pragma unroll
        for (int m = 0; m < 2; ++m)
#pragma unroll
          for (int n = 0; n < 4; ++n)
#pragma unroll
            for (int r = 0; r < 4; ++r)
              sc[m][n][r] = fmaf(sc[m][n][r], cs, pm_add[n]);
      }

      // tile max + defer-max (THR=8 in exp2 domain)
      float mx[2][4];
      bool grow = false;
#pragma unroll
      for (int m = 0; m < 2; ++m)
#pragma unroll
        for (int r = 0; r < 4; ++r) {
          float v = fmaxf(fmaxf(sc[m][0][r], sc[m][1][r]),
                          fmaxf(sc[m][2][r], sc[m][3][r]));
#pragma unroll
          for (int off = 1; off < 16; off <<= 1)
            v = fmaxf(v, __shfl_xor(v, off, 64));
          mx[m][r] = v;
          grow = grow || (v > mrow[m][r] + 8.f);
        }
      if (__any(grow)) {
#pragma unroll
        for (int m = 0; m < 2; ++m)
#pragma unroll
          for (int r = 0; r < 4; ++r) {
            const float mnew = fmaxf(mrow[m][r], mx[m][r]);
            const float corr = exp2f(mrow[m][r] - mnew);
            mrow[m][r] = mnew;
            lrow[m][r] *= corr;
#pragma unroll
            for (int nd = 0; nd < 4; ++nd) oacc[m][nd][r] *= corr;
          }
      }

      // P = exp2(s - m), row sums
#pragma unroll
      for (int m = 0; m < 2; ++m)
#pragma unroll
        for (int r = 0; r < 4; ++r) {
          float rs = 0.f;
#pragma unroll
          for (int n = 0; n < 4; ++n) {
            const float p = exp2f(sc[m][n][r] - mrow[m][r]);
            sc[m][n][r] = p;
            rs += p;
          }
#pragma unroll
          for (int off = 1; off < 16; off <<= 1)
            rs += __shfl_xor(rs, off, 64);
          lrow[m][r] += rs;
        }

      // P -> LDS (bf16)
      unsigned short* pw = &Pl[wave][0];
#pragma unroll
      for (int m = 0; m < 2; ++m)
#pragma unroll
        for (int n = 0; n < 4; ++n)
#pragma unroll
          for (int r = 0; r < 4; ++r)
            pw[(m * 16 + g * 4 + r) * 72 + n * 16 + cl] = f2bf(sc[m][n][r]);

      // O += P @ V
#pragma unroll
      for (int kk = 0; kk < 2; ++kk) {
        short8 pf[2], vf[4];
#pragma unroll
        for (int m = 0; m < 2; ++m)
          pf[m] = *(const short8*)(pw + (m * 16 + cl) * 72 + kk * 32 + g * 8);
#pragma unroll
        for (int nd = 0; nd < 4; ++nd) {
          const int row = nd * 16 + cl;
          const int colb = ((kk * 32 + g * 8) * 2) ^ ((row & 7) << 4);
          vf[nd] = *(const short8*)((const char*)Vl + row * 128 + colb);
        }
#pragma unroll
        for (int m = 0; m < 2; ++m)
#pragma unroll
          for (int nd = 0; nd < 4; ++nd)
            oacc[m][nd] = __builtin_amdgcn_mfma_f32_16x16x32_bf16(pf[m], vf[nd], oacc[m][nd], 0, 0, 0);
      }
    }
    __syncthreads();
  }

  // normalize + write
#pragma unroll
  for (int m = 0; m < 2; ++m) {
    float inv[4];
#pragma unroll
    for (int r = 0; r < 4; ++r) inv[r] = 1.f / lrow[m][r];
#pragma unroll
    for (int nd = 0; nd < 4; ++nd)
#pragma unroll
      for (int r = 0; r < 4; ++r) {
        const int qg = qw + m * 16 + g * 4 + r;
        Out[(size_t)(b * S_ + qg) * D_ + h * HD_ + nd * 16 + cl] =
            f2bf(oacc[m][nd][r] * inv[r]);
      }
  }
}

// ---------------- launch ----------------
extern "C" void kernel_launch(void* const* d_in, const int* in_sizes, int n_in,
                              void* d_out, int out_size, void* d_ws, size_t ws_size,
                              hipStream_t stream) {
  (void)in_sizes; (void)n_in; (void)out_size; (void)ws_size;
  const float* q  = (const float*)d_in[0];
  const float* k  = (const float*)d_in[1];
  const float* v  = (const float*)d_in[2];
  const unsigned char* pm = (const unsigned char*)d_in[3];
  const float* Wq = (const float*)d_in[4];
  const float* bq = (const float*)d_in[5];
  const float* Wk = (const float*)d_in[6];
  const float* bk = (const float*)d_in[7];
  const float* Wv = (const float*)d_in[8];
  const float* bv = (const float*)d_in[9];
  const float* Wo = (const float*)d_in[10];
  const float* bo = (const float*)d_in[11];

  char* ws = (char*)d_ws;
  const size_t MB = 1024 * 1024;
  unsigned short* qb  = (unsigned short*)(ws + 0 * MB);
  unsigned short* kb  = (unsigned short*)(ws + 16 * MB);
  unsigned short* vb  = (unsigned short*)(ws + 32 * MB);
  unsigned short* Wqb = (unsigned short*)(ws + 48 * MB);
  unsigned short* Wkb = (unsigned short*)(ws + 50 * MB);
  unsigned short* Wvb = (unsigned short*)(ws + 52 * MB);
  unsigned short* Wob = (unsigned short*)(ws + 54 * MB);
  unsigned short* Qp  = (unsigned short*)(ws + 56 * MB);
  unsigned short* Kp  = (unsigned short*)(ws + 72 * MB);
  unsigned short* Vt  = (unsigned short*)(ws + 88 * MB);
  unsigned short* AO  = (unsigned short*)(ws + 104 * MB);

  const int n4_qkv = B_ * S_ * D_ / 4;
  const int n4_w   = 1024 * 1024 / 4;
  cvt3_f32_to_bf16<<<dim3(n4_qkv / 256, 3), dim3(256), 0, stream>>>(q, k, v, qb, kb, vb, n4_qkv);
  cvt4_f32_to_bf16<<<dim3(n4_w / 256, 4), dim3(256), 0, stream>>>(Wq, Wk, Wv, Wo, Wqb, Wkb, Wvb, Wob, n4_w);

  gemm_qkv<<<dim3(8, 64, 3), dim3(256), 0, stream>>>(qb, kb, vb, Wqb, Wkb, Wvb,
                                                     bq, bk, bv, Qp, Kp, Vt);

  attn_fwd<<<dim3(16, 64), dim3(256), 0, stream>>>(Qp, Kp, Vt, pm, AO);

  gemm_o<<<dim3(8, 64), dim3(256), 0, stream>>>(AO, Wob, bo, (float*)d_out);
}